// Round 10
// baseline (377.841 us; speedup 1.0000x reference)
//
#include <hip/hip_runtime.h>
#include <hip/hip_cooperative_groups.h>

#define NEG_SLOPE 0.2f
#define EPSV 1e-16f

namespace cg = cooperative_groups;

typedef float f32x4 __attribute__((ext_vector_type(4)));
typedef float f32x2 __attribute__((ext_vector_type(2)));
typedef short s16x2 __attribute__((ext_vector_type(2)));
typedef unsigned u32x2 __attribute__((ext_vector_type(2)));

// Monotone f32 <-> u32 mapping so atomicMax(u32) implements float max.
__device__ __forceinline__ unsigned fenc(float f) {
    unsigned b = __float_as_uint(f);
    return b ^ ((b & 0x80000000u) ? 0xFFFFFFFFu : 0x80000000u);
}
__device__ __forceinline__ float fdec(unsigned u) {
    unsigned b = (u & 0x80000000u) ? (u ^ 0x80000000u) : ~u;
    return __uint_as_float(b);
}
#define FENC_NEG_INF 0x007FFFFFu   // fenc(-inf)

__device__ __forceinline__ unsigned f32_to_bf16_rne(float f) {
    unsigned u = __float_as_uint(f);
    unsigned lsb = (u >> 16) & 1u;
    return (u + 0x7FFFu + lsb) >> 16;   // values are positive finite
}

// One packed atomic adds 2 bf16 lanes: native GLOBAL_ATOMIC_PK_ADD_BF16.
__device__ __forceinline__ void pk_atomic_add_bf16(unsigned* addr, float a, float b) {
#if __has_builtin(__builtin_amdgcn_global_atomic_fadd_v2bf16)
    s16x2 v;
    v.x = (short)f32_to_bf16_rne(a);
    v.y = (short)f32_to_bf16_rne(b);
    typedef __attribute__((address_space(1))) s16x2 gs16x2;
    __builtin_amdgcn_global_atomic_fadd_v2bf16((gs16x2*)(void*)addr, v);
#else
    unsigned old = *addr, assumed;
    do {
        assumed = old;
        float lo = __uint_as_float((assumed & 0xFFFFu) << 16) + a;
        float hi = __uint_as_float(assumed & 0xFFFF0000u) + b;
        unsigned nv = (f32_to_bf16_rne(hi) << 16) | (f32_to_bf16_rne(lo) & 0xFFFFu);
        old = atomicCAS(addr, assumed, nv);
    } while (old != assumed);
#endif
}

// Detect int64 vs int32 edge_index on device.
__global__ void detect_idx_kernel(const unsigned* __restrict__ ei32,
                                  int* __restrict__ flag) {
    __shared__ int anynz;
    if (threadIdx.x == 0) anynz = 0;
    __syncthreads();
    unsigned v = ei32[2 * threadIdx.x + 1];
    if (v != 0u) anynz = 1;
    __syncthreads();
    if (threadIdx.x == 0) *flag = (anynz ? 0 : 1);   // 1 => int64
}

__device__ __forceinline__ int load_idx(const void* ei, int is64, size_t k) {
    if (is64) return (int)__builtin_nontemporal_load(&((const long long*)ei)[k]);
    return __builtin_nontemporal_load(&((const int*)ei)[k]);
}

// K1: per-node logits per head; zero pk nsum; init gmax.
__global__ void node_scores_kernel(const float* __restrict__ nf,
                                   const float* __restrict__ sfs,
                                   const float* __restrict__ sft,
                                   float* __restrict__ ss,
                                   float* __restrict__ st,
                                   unsigned* __restrict__ nsum_zero,
                                   unsigned* __restrict__ gmax,
                                   int NH, int nzero) {
    int i = blockIdx.x * blockDim.x + threadIdx.x;
    if (i >= NH) return;
    if (i == 0) *gmax = FENC_NEG_INF;
    for (int k = i; k < nzero; k += NH) nsum_zero[k] = 0u;
    int h = i & 3;
    const float4* __restrict__ row = (const float4*)(nf + (size_t)i * 32);
    const float4* __restrict__ as  = (const float4*)(sfs + h * 32);
    const float4* __restrict__ at  = (const float4*)(sft + h * 32);
    float accs = 0.f, acct = 0.f;
#pragma unroll
    for (int q = 0; q < 8; ++q) {
        float4 v = row[q];
        float4 a = as[q];
        float4 b = at[q];
        accs += v.x * a.x + v.y * a.y + v.z * a.z + v.w * a.w;
        acct += v.x * b.x + v.y * b.y + v.z * b.z + v.w * b.w;
    }
    ss[i] = accs;
    st[i] = acct;
}

// K2 (cooperative): phase A: per (edge,head-pair) p = exp(leaky_relu(ss+st)),
// ONE pk bf16 atomic into nsum_pk, p/trg kept in registers; track max.
// grid.sync(). Phase B: att = p / (bf16(nsum) + eps*e^c), nt store.
// Identity exp(lr-c)/(S+eps) == exp(lr)/(S'+eps*e^c) -> no max pre-pass.
// MAXI register slots; items beyond MAXI*stride (never for E<=2M at 1024x256)
// are recomputed in phase B (their atomics still happened in phase A).
#define MAXI 8
__global__ void fused_edge_kernel(const void* __restrict__ ei,
                                  const int* __restrict__ flag,
                                  const float* __restrict__ ss,
                                  const float* __restrict__ st,
                                  unsigned* __restrict__ nsum_pk,
                                  unsigned* __restrict__ gmax,
                                  float* __restrict__ out,
                                  int E) {
    __shared__ float red[256];
    int is64 = *flag;
    int n2 = E * 2;
    int stride = gridDim.x * blockDim.x;
    int base = blockIdx.x * blockDim.x + threadIdx.x;

    f32x2 preg[MAXI];
    int   treg[MAXI];
    float lmax = -__builtin_inff();

    // ---- phase A: exp + scatter-add (ALL items), cache first MAXI in regs ----
    int it = 0;
    for (int i = base; i < n2; i += stride, ++it) {
        int e = i >> 1, hp = i & 1;
        int trg = load_idx(ei, is64, e);
        int src = load_idx(ei, is64, (size_t)E + e);
        f32x2 a = *(const f32x2*)(ss + (size_t)src * 4 + hp * 2);
        f32x2 b = *(const f32x2*)(st + (size_t)trg * 4 + hp * 2);
        float s0 = a.x + b.x, s1 = a.y + b.y;
        float lr0 = s0 > 0.f ? s0 : NEG_SLOPE * s0;
        float lr1 = s1 > 0.f ? s1 : NEG_SLOPE * s1;
        lmax = fmaxf(lmax, fmaxf(lr0, lr1));
        float p0 = __expf(lr0), p1 = __expf(lr1);
        if (it < MAXI) {
            f32x2 pv; pv.x = p0; pv.y = p1;
#pragma unroll
            for (int k = 0; k < MAXI; ++k)
                if (k == it) { preg[k] = pv; treg[k] = trg; }
        }
        pk_atomic_add_bf16(nsum_pk + (size_t)trg * 2 + hp, p0, p1);
    }

    red[threadIdx.x] = lmax;
    __syncthreads();
    for (int off = 128; off > 0; off >>= 1) {
        if (threadIdx.x < off)
            red[threadIdx.x] = fmaxf(red[threadIdx.x], red[threadIdx.x + off]);
        __syncthreads();
    }
    if (threadIdx.x == 0) atomicMax(gmax, fenc(red[0]));

    cg::this_grid().sync();

    // ---- phase B: divide + write attention ----
    float de = EPSV * __expf(fdec(*gmax));
    it = 0;
    for (int i = base; i < n2; i += stride, ++it) {
        int e = i >> 1, hp = i & 1;
        f32x2 pv;
        int trg;
        if (it < MAXI) {
#pragma unroll
            for (int k = 0; k < MAXI; ++k)
                if (k == it) { pv = preg[k]; trg = treg[k]; }
        } else {  // overflow path: recompute (atomics already done in phase A)
            trg = load_idx(ei, is64, e);
            int src = load_idx(ei, is64, (size_t)E + e);
            f32x2 a = *(const f32x2*)(ss + (size_t)src * 4 + hp * 2);
            f32x2 b = *(const f32x2*)(st + (size_t)trg * 4 + hp * 2);
            float s0 = a.x + b.x, s1 = a.y + b.y;
            float lr0 = s0 > 0.f ? s0 : NEG_SLOPE * s0;
            float lr1 = s1 > 0.f ? s1 : NEG_SLOPE * s1;
            pv.x = __expf(lr0); pv.y = __expf(lr1);
        }
        unsigned u = nsum_pk[(size_t)trg * 2 + hp];
        f32x2 d;
        d.x = __uint_as_float((u & 0xFFFFu) << 16);
        d.y = __uint_as_float(u & 0xFFFF0000u);
        f32x2 a = pv / (d + de);
        __builtin_nontemporal_store(a, (f32x2*)(out + (size_t)e * 4 + hp * 2));
    }
}

// K3: feature gather; 16 lanes x 32B = 512B per edge, 2 loads in flight,
// nt stores, loop kept pure (r7 lesson).
__global__ void gather_feat_kernel(const void* __restrict__ ei,
                                   const int* __restrict__ flag,
                                   const f32x4* __restrict__ nf4,
                                   f32x4* __restrict__ out4, int E) {
    int is64 = *flag;
    int n = E * 16;
    int stride = gridDim.x * blockDim.x;
    for (int t = blockIdx.x * blockDim.x + threadIdx.x; t < n; t += stride) {
        int e = t >> 4, q = (t & 15) * 2;
        int src = load_idx(ei, is64, (size_t)E + e);
        const f32x4* sp = nf4 + (size_t)src * 32 + q;
        f32x4 v0 = sp[0];
        f32x4 v1 = sp[1];
        f32x4* dp = out4 + (size_t)e * 32 + q;
        __builtin_nontemporal_store(v0, dp);
        __builtin_nontemporal_store(v1, dp + 1);
    }
}

// ---------- fallback (ws too small): r9 separate-kernel pipeline ----------
__device__ __forceinline__ float edge_lr_rc(const void* ei, int is64,
                                            const float* ss, const float* st,
                                            int E, int e, int h, int* trg_out) {
    int trg = load_idx(ei, is64, e);
    int src = load_idx(ei, is64, (size_t)E + e);
    if (trg_out) *trg_out = trg;
    float s = ss[src * 4 + h] + st[trg * 4 + h];
    return s > 0.f ? s : NEG_SLOPE * s;
}

__global__ void zero_fb_kernel(float* __restrict__ nsum, int n) {
    int i = blockIdx.x * blockDim.x + threadIdx.x;
    if (i < n) nsum[i] = 0.f;
}

__global__ void edge_exp_sum_fb_kernel(const void* __restrict__ ei,
                                       const int* __restrict__ flag,
                                       const float* __restrict__ ss,
                                       const float* __restrict__ st,
                                       float* __restrict__ nsum,
                                       unsigned* __restrict__ gmax, int E) {
    __shared__ float red[256];
    int is64 = *flag;
    int n4 = E * 4;
    int stride = gridDim.x * blockDim.x;
    float lmax = -__builtin_inff();
    for (int i = blockIdx.x * blockDim.x + threadIdx.x; i < n4; i += stride) {
        int trg;
        float lr = edge_lr_rc(ei, is64, ss, st, E, i >> 2, i & 3, &trg);
        lmax = fmaxf(lmax, lr);
        atomicAdd(&nsum[trg * 4 + (i & 3)], __expf(lr));
    }
    red[threadIdx.x] = lmax;
    __syncthreads();
    for (int off = 128; off > 0; off >>= 1) {
        if (threadIdx.x < off)
            red[threadIdx.x] = fmaxf(red[threadIdx.x], red[threadIdx.x + off]);
        __syncthreads();
    }
    if (threadIdx.x == 0) atomicMax(gmax, fenc(red[0]));
}

__global__ void att_fb_kernel(const void* __restrict__ ei,
                              const int* __restrict__ flag,
                              const float* __restrict__ ss,
                              const float* __restrict__ st,
                              const unsigned* __restrict__ gmax,
                              const float* __restrict__ nsum,
                              float* __restrict__ out, int E) {
    int i = blockIdx.x * blockDim.x + threadIdx.x;
    if (i >= E * 4) return;
    int is64 = *flag;
    float de = EPSV * __expf(fdec(*gmax));
    int trg;
    float lr = edge_lr_rc(ei, is64, ss, st, E, i >> 2, i & 3, &trg);
    float a = __expf(lr) / (nsum[trg * 4 + (i & 3)] + de);
    __builtin_nontemporal_store(a, &out[i]);
}

extern "C" void kernel_launch(void* const* d_in, const int* in_sizes, int n_in,
                              void* d_out, int out_size, void* d_ws, size_t ws_size,
                              hipStream_t stream) {
    const float* nf  = (const float*)d_in[0];
    const float* sfs = (const float*)d_in[1];
    const float* sft = (const float*)d_in[2];
    const void*  ei  = d_in[3];

    const int NH = in_sizes[0] / 32;   // N*H (F = 32)
    const int N  = NH / 4;
    const int E  = in_sizes[3] / 2;

    float* out = (float*)d_out;
    float* ws  = (float*)d_ws;

    // Layout: ss[NH] | st[NH] | flag,gmax,pad,pad | nsum_pk[N*2 u32]
    float*    ss      = ws;
    float*    st      = ws + NH;
    int*      flag    = (int*)(ws + 2 * (size_t)NH);
    unsigned* gmax    = (unsigned*)(flag + 1);
    unsigned* nsum_pk = (unsigned*)(ws + 2 * (size_t)NH + 4);

    size_t need = ((size_t)2 * NH + 4 + (size_t)N * 2) * 4;
    bool lean = ws_size >= need;

    const int B = 256;

    detect_idx_kernel<<<1, 256, 0, stream>>>((const unsigned*)ei, flag);

    if (lean) {
        node_scores_kernel<<<(NH + B - 1) / B, B, 0, stream>>>(
            nf, sfs, sft, ss, st, nsum_pk, gmax, NH, N * 2);

        // Cooperative fused exp/sum + att: 1024 blocks co-resident
        // (<=128 VGPR -> >=4 blocks/CU on 256 CUs).
        void* args[] = {(void*)&ei, (void*)&flag, (void*)&ss, (void*)&st,
                        (void*)&nsum_pk, (void*)&gmax, (void*)&out, (void*)&E};
        hipLaunchCooperativeKernel((const void*)fused_edge_kernel,
                                   dim3(1024), dim3(B), args, 0, stream);

        gather_feat_kernel<<<4096, B, 0, stream>>>(
            ei, flag, (const f32x4*)nf, (f32x4*)(out + (size_t)E * 4), E);
    } else {
        float* nsum_fb = (float*)(gmax + 1);
        node_scores_kernel<<<(NH + B - 1) / B, B, 0, stream>>>(
            nf, sfs, sft, ss, st, (unsigned*)nsum_fb, gmax, NH, 0);
        zero_fb_kernel<<<(NH + B - 1) / B, B, 0, stream>>>(nsum_fb, NH);
        edge_exp_sum_fb_kernel<<<2048, B, 0, stream>>>(ei, flag, ss, st,
                                                       nsum_fb, gmax, E);
        att_fb_kernel<<<(E * 4 + B - 1) / B, B, 0, stream>>>(ei, flag, ss, st,
                                                             gmax, nsum_fb, out, E);
        gather_feat_kernel<<<4096, B, 0, stream>>>(
            ei, flag, (const f32x4*)nf, (f32x4*)(out + (size_t)E * 4), E);
    }
}

// Round 11
// 311.288 us; speedup vs baseline: 1.2138x; 1.2138x over previous
//
#include <hip/hip_runtime.h>

#define NEG_SLOPE 0.2f
#define EPSV 1e-16f

typedef float f32x4 __attribute__((ext_vector_type(4)));
typedef float f32x2 __attribute__((ext_vector_type(2)));
typedef short s16x2 __attribute__((ext_vector_type(2)));
typedef unsigned u32x2 __attribute__((ext_vector_type(2)));

// Monotone f32 <-> u32 mapping so atomicMax(u32) implements float max.
__device__ __forceinline__ unsigned fenc(float f) {
    unsigned b = __float_as_uint(f);
    return b ^ ((b & 0x80000000u) ? 0xFFFFFFFFu : 0x80000000u);
}
__device__ __forceinline__ float fdec(unsigned u) {
    unsigned b = (u & 0x80000000u) ? (u ^ 0x80000000u) : ~u;
    return __uint_as_float(b);
}
#define FENC_NEG_INF 0x007FFFFFu   // fenc(-inf)

__device__ __forceinline__ unsigned f32_to_bf16_rne(float f) {
    unsigned u = __float_as_uint(f);
    unsigned lsb = (u >> 16) & 1u;
    return (u + 0x7FFFu + lsb) >> 16;   // values are positive finite
}

// One packed atomic adds 2 bf16 lanes: native GLOBAL_ATOMIC_PK_ADD_BF16.
__device__ __forceinline__ void pk_atomic_add_bf16(unsigned* addr, float a, float b) {
#if __has_builtin(__builtin_amdgcn_global_atomic_fadd_v2bf16)
    s16x2 v;
    v.x = (short)f32_to_bf16_rne(a);
    v.y = (short)f32_to_bf16_rne(b);
    typedef __attribute__((address_space(1))) s16x2 gs16x2;
    __builtin_amdgcn_global_atomic_fadd_v2bf16((gs16x2*)(void*)addr, v);
#else
    unsigned old = *addr, assumed;
    do {
        assumed = old;
        float lo = __uint_as_float((assumed & 0xFFFFu) << 16) + a;
        float hi = __uint_as_float(assumed & 0xFFFF0000u) + b;
        unsigned nv = (f32_to_bf16_rne(hi) << 16) | (f32_to_bf16_rne(lo) & 0xFFFFu);
        old = atomicCAS(addr, assumed, nv);
    } while (old != assumed);
#endif
}

// Detect int64 vs int32 edge_index on device.
__global__ void detect_idx_kernel(const unsigned* __restrict__ ei32,
                                  int* __restrict__ flag) {
    __shared__ int anynz;
    if (threadIdx.x == 0) anynz = 0;
    __syncthreads();
    unsigned v = ei32[2 * threadIdx.x + 1];
    if (v != 0u) anynz = 1;
    __syncthreads();
    if (threadIdx.x == 0) *flag = (anynz ? 0 : 1);   // 1 => int64
}

// Cached index load: ei is read by 3 kernels -- let it live in L2/L3.
__device__ __forceinline__ int load_idx(const void* ei, int is64, size_t k) {
    if (is64) return (int)((const long long*)ei)[k];
    return ((const int*)ei)[k];
}

// K1: per-node logits per head; zero pk nsum; init gmax.
__global__ void node_scores_kernel(const float* __restrict__ nf,
                                   const float* __restrict__ sfs,
                                   const float* __restrict__ sft,
                                   float* __restrict__ ss,
                                   float* __restrict__ st,
                                   unsigned* __restrict__ nsum_zero,
                                   unsigned* __restrict__ gmax,
                                   int NH, int nzero) {
    int i = blockIdx.x * blockDim.x + threadIdx.x;
    if (i >= NH) return;
    if (i == 0) *gmax = FENC_NEG_INF;
    for (int k = i; k < nzero; k += NH) nsum_zero[k] = 0u;
    int h = i & 3;
    const float4* __restrict__ row = (const float4*)(nf + (size_t)i * 32);
    const float4* __restrict__ as  = (const float4*)(sfs + h * 32);
    const float4* __restrict__ at  = (const float4*)(sft + h * 32);
    float accs = 0.f, acct = 0.f;
#pragma unroll
    for (int q = 0; q < 8; ++q) {
        float4 v = row[q];
        float4 a = as[q];
        float4 b = at[q];
        accs += v.x * a.x + v.y * a.y + v.z * a.z + v.w * a.w;
        acct += v.x * b.x + v.y * b.y + v.z * b.z + v.w * b.w;
    }
    ss[i] = accs;
    st[i] = acct;
}

// K2: ONE thread per edge: p[h] = exp(leaky_relu(ss[src]+st[trg])) for all 4
// heads -> pbuf (REGULAR store: consumed by K3, keep it cached), two pk bf16
// atomics into nsum_pk[trg]; track running max.
// Identity (validated r6+): exp(lr-c)/(S+eps) == exp(lr)/(S'+eps*e^c) -> no
// max pre-pass; c only used in the final divide.
__global__ void edge_exp_sum_kernel(const void* __restrict__ ei,
                                    const int* __restrict__ flag,
                                    const float* __restrict__ ss,
                                    const float* __restrict__ st,
                                    float* __restrict__ pbuf,
                                    unsigned* __restrict__ nsum_pk,
                                    unsigned* __restrict__ gmax,
                                    int E) {
    __shared__ float red[256];
    int is64 = *flag;
    int stride = gridDim.x * blockDim.x;
    float lmax = -__builtin_inff();
    for (int e = blockIdx.x * blockDim.x + threadIdx.x; e < E; e += stride) {
        int trg = load_idx(ei, is64, e);
        int src = load_idx(ei, is64, (size_t)E + e);
        f32x4 a = *(const f32x4*)(ss + (size_t)src * 4);
        f32x4 b = *(const f32x4*)(st + (size_t)trg * 4);
        f32x4 s = a + b;
        f32x4 p;
#pragma unroll
        for (int h = 0; h < 4; ++h) {
            float lr = s[h] > 0.f ? s[h] : NEG_SLOPE * s[h];
            lmax = fmaxf(lmax, lr);
            p[h] = __expf(lr);
        }
        *(f32x4*)(pbuf + (size_t)e * 4) = p;   // cached: K3 reads it next
        pk_atomic_add_bf16(nsum_pk + (size_t)trg * 2 + 0, p[0], p[1]);
        pk_atomic_add_bf16(nsum_pk + (size_t)trg * 2 + 1, p[2], p[3]);
    }
    red[threadIdx.x] = lmax;
    __syncthreads();
    for (int off = 128; off > 0; off >>= 1) {
        if (threadIdx.x < off)
            red[threadIdx.x] = fmaxf(red[threadIdx.x], red[threadIdx.x + off]);
        __syncthreads();
    }
    if (threadIdx.x == 0) atomicMax(gmax, fenc(red[0]));
}

// K3: att = p / (bf16_decode(nsum) + eps*e^c); per edge, float4 in, nt out.
__global__ void att_pk_kernel(const void* __restrict__ ei,
                              const int* __restrict__ flag,
                              const float* __restrict__ pbuf,
                              const unsigned* __restrict__ nsum_pk,
                              const unsigned* __restrict__ gmax,
                              float* __restrict__ out,
                              int E) {
    int is64 = *flag;
    float de = EPSV * __expf(fdec(*gmax));
    int stride = gridDim.x * blockDim.x;
    for (int e = blockIdx.x * blockDim.x + threadIdx.x; e < E; e += stride) {
        int trg = load_idx(ei, is64, e);
        u32x2 u = *(const u32x2*)(nsum_pk + (size_t)trg * 2);
        f32x4 d;
        d.x = __uint_as_float((u.x & 0xFFFFu) << 16);
        d.y = __uint_as_float(u.x & 0xFFFF0000u);
        d.z = __uint_as_float((u.y & 0xFFFFu) << 16);
        d.w = __uint_as_float(u.y & 0xFFFF0000u);
        f32x4 p = *(const f32x4*)(pbuf + (size_t)e * 4);
        f32x4 a = p / (d + de);
        __builtin_nontemporal_store(a, (f32x4*)(out + (size_t)e * 4));
    }
}

// K4: feature gather; 16 lanes x 32B = 512B per edge, 2 independent loads in
// flight per thread, nt stores, loop kept pure (r7 lesson).
__global__ void gather_feat_kernel(const void* __restrict__ ei,
                                   const int* __restrict__ flag,
                                   const f32x4* __restrict__ nf4,
                                   f32x4* __restrict__ out4, int E) {
    int is64 = *flag;
    int n = E * 16;
    int stride = gridDim.x * blockDim.x;
    for (int t = blockIdx.x * blockDim.x + threadIdx.x; t < n; t += stride) {
        int e = t >> 4, q = (t & 15) * 2;
        int src = load_idx(ei, is64, (size_t)E + e);
        const f32x4* sp = nf4 + (size_t)src * 32 + q;
        f32x4 v0 = sp[0];
        f32x4 v1 = sp[1];
        f32x4* dp = out4 + (size_t)e * 32 + q;
        __builtin_nontemporal_store(v0, dp);
        __builtin_nontemporal_store(v1, dp + 1);
    }
}

// ---------- fallback (ws too small for pbuf): recompute pipeline ----------
__device__ __forceinline__ float edge_lr_rc(const void* ei, int is64,
                                            const float* ss, const float* st,
                                            int E, int e, int h, int* trg_out) {
    int trg = load_idx(ei, is64, e);
    int src = load_idx(ei, is64, (size_t)E + e);
    if (trg_out) *trg_out = trg;
    float s = ss[src * 4 + h] + st[trg * 4 + h];
    return s > 0.f ? s : NEG_SLOPE * s;
}

__global__ void zero_fb_kernel(float* __restrict__ nsum, int n) {
    int i = blockIdx.x * blockDim.x + threadIdx.x;
    if (i < n) nsum[i] = 0.f;
}

__global__ void edge_exp_sum_fb_kernel(const void* __restrict__ ei,
                                       const int* __restrict__ flag,
                                       const float* __restrict__ ss,
                                       const float* __restrict__ st,
                                       float* __restrict__ nsum,
                                       unsigned* __restrict__ gmax, int E) {
    __shared__ float red[256];
    int is64 = *flag;
    int n4 = E * 4;
    int stride = gridDim.x * blockDim.x;
    float lmax = -__builtin_inff();
    for (int i = blockIdx.x * blockDim.x + threadIdx.x; i < n4; i += stride) {
        int trg;
        float lr = edge_lr_rc(ei, is64, ss, st, E, i >> 2, i & 3, &trg);
        lmax = fmaxf(lmax, lr);
        atomicAdd(&nsum[trg * 4 + (i & 3)], __expf(lr));
    }
    red[threadIdx.x] = lmax;
    __syncthreads();
    for (int off = 128; off > 0; off >>= 1) {
        if (threadIdx.x < off)
            red[threadIdx.x] = fmaxf(red[threadIdx.x], red[threadIdx.x + off]);
        __syncthreads();
    }
    if (threadIdx.x == 0) atomicMax(gmax, fenc(red[0]));
}

__global__ void att_fb_kernel(const void* __restrict__ ei,
                              const int* __restrict__ flag,
                              const float* __restrict__ ss,
                              const float* __restrict__ st,
                              const unsigned* __restrict__ gmax,
                              const float* __restrict__ nsum,
                              float* __restrict__ out, int E) {
    int i = blockIdx.x * blockDim.x + threadIdx.x;
    if (i >= E * 4) return;
    int is64 = *flag;
    float de = EPSV * __expf(fdec(*gmax));
    int trg;
    float lr = edge_lr_rc(ei, is64, ss, st, E, i >> 2, i & 3, &trg);
    float a = __expf(lr) / (nsum[trg * 4 + (i & 3)] + de);
    __builtin_nontemporal_store(a, &out[i]);
}

extern "C" void kernel_launch(void* const* d_in, const int* in_sizes, int n_in,
                              void* d_out, int out_size, void* d_ws, size_t ws_size,
                              hipStream_t stream) {
    const float* nf  = (const float*)d_in[0];
    const float* sfs = (const float*)d_in[1];
    const float* sft = (const float*)d_in[2];
    const void*  ei  = d_in[3];

    const int NH = in_sizes[0] / 32;   // N*H (F = 32)
    const int N  = NH / 4;
    const int E  = in_sizes[3] / 2;

    float* out = (float*)d_out;
    float* ws  = (float*)d_ws;

    // Layout: ss[NH] | st[NH] | flag,gmax,pad,pad | pbuf[E*4] | nsum_pk[N*2 u32]
    float*    ss      = ws;
    float*    st      = ws + NH;
    int*      flag    = (int*)(ws + 2 * (size_t)NH);
    unsigned* gmax    = (unsigned*)(flag + 1);
    float*    pbuf    = ws + 2 * (size_t)NH + 4;
    unsigned* nsum_pk = (unsigned*)(pbuf + (size_t)E * 4);

    size_t need = ((size_t)2 * NH + 4 + (size_t)E * 4 + (size_t)N * 2) * 4;
    bool lean = ws_size >= need;

    const int B = 256;

    detect_idx_kernel<<<1, 256, 0, stream>>>((const unsigned*)ei, flag);

    if (lean) {
        node_scores_kernel<<<(NH + B - 1) / B, B, 0, stream>>>(
            nf, sfs, sft, ss, st, nsum_pk, gmax, NH, N * 2);
        edge_exp_sum_kernel<<<2048, B, 0, stream>>>(ei, flag, ss, st, pbuf,
                                                    nsum_pk, gmax, E);
        att_pk_kernel<<<2048, B, 0, stream>>>(ei, flag, pbuf, nsum_pk, gmax,
                                              out, E);
        gather_feat_kernel<<<4096, B, 0, stream>>>(
            ei, flag, (const f32x4*)nf, (f32x4*)(out + (size_t)E * 4), E);
    } else {
        // minimal-ws fallback: f32 nsum right after gmax
        float* nsum_fb = (float*)(gmax + 1);
        node_scores_kernel<<<(NH + B - 1) / B, B, 0, stream>>>(
            nf, sfs, sft, ss, st, (unsigned*)nsum_fb, gmax, NH, 0);
        zero_fb_kernel<<<(NH + B - 1) / B, B, 0, stream>>>(nsum_fb, NH);
        edge_exp_sum_fb_kernel<<<2048, B, 0, stream>>>(ei, flag, ss, st,
                                                       nsum_fb, gmax, E);
        att_fb_kernel<<<(E * 4 + B - 1) / B, B, 0, stream>>>(ei, flag, ss, st,
                                                             gmax, nsum_fb, out, E);
        gather_feat_kernel<<<4096, B, 0, stream>>>(
            ei, flag, (const f32x4*)nf, (f32x4*)(out + (size_t)E * 4), E);
    }
}

// Round 12
// 245.522 us; speedup vs baseline: 1.5389x; 1.2679x over previous
//
#include <hip/hip_runtime.h>

#define NEG_SLOPE 0.2f
#define EPSV 1e-16f

typedef float f32x4 __attribute__((ext_vector_type(4)));
typedef float f32x2 __attribute__((ext_vector_type(2)));
typedef short s16x2 __attribute__((ext_vector_type(2)));

// Monotone f32 <-> u32 mapping so atomicMax(u32) implements float max.
__device__ __forceinline__ unsigned fenc(float f) {
    unsigned b = __float_as_uint(f);
    return b ^ ((b & 0x80000000u) ? 0xFFFFFFFFu : 0x80000000u);
}
__device__ __forceinline__ float fdec(unsigned u) {
    unsigned b = (u & 0x80000000u) ? (u ^ 0x80000000u) : ~u;
    return __uint_as_float(b);
}
#define FENC_NEG_INF 0x007FFFFFu   // fenc(-inf)

__device__ __forceinline__ unsigned f32_to_bf16_rne(float f) {
    unsigned u = __float_as_uint(f);
    unsigned lsb = (u >> 16) & 1u;
    return (u + 0x7FFFu + lsb) >> 16;   // values are positive finite
}

// One packed atomic adds 2 bf16 lanes: native GLOBAL_ATOMIC_PK_ADD_BF16.
__device__ __forceinline__ void pk_atomic_add_bf16(unsigned* addr, float a, float b) {
#if __has_builtin(__builtin_amdgcn_global_atomic_fadd_v2bf16)
    s16x2 v;
    v.x = (short)f32_to_bf16_rne(a);
    v.y = (short)f32_to_bf16_rne(b);
    typedef __attribute__((address_space(1))) s16x2 gs16x2;
    __builtin_amdgcn_global_atomic_fadd_v2bf16((gs16x2*)(void*)addr, v);
#else
    unsigned old = *addr, assumed;
    do {
        assumed = old;
        float lo = __uint_as_float((assumed & 0xFFFFu) << 16) + a;
        float hi = __uint_as_float(assumed & 0xFFFF0000u) + b;
        unsigned nv = (f32_to_bf16_rne(hi) << 16) | (f32_to_bf16_rne(lo) & 0xFFFFu);
        old = atomicCAS(addr, assumed, nv);
    } while (old != assumed);
#endif
}

// Detect int64 vs int32 edge_index on device.
__global__ void detect_idx_kernel(const unsigned* __restrict__ ei32,
                                  int* __restrict__ flag) {
    __shared__ int anynz;
    if (threadIdx.x == 0) anynz = 0;
    __syncthreads();
    unsigned v = ei32[2 * threadIdx.x + 1];
    if (v != 0u) anynz = 1;
    __syncthreads();
    if (threadIdx.x == 0) *flag = (anynz ? 0 : 1);   // 1 => int64
}

// nt index load (r9-proven).
__device__ __forceinline__ int load_idx(const void* ei, int is64, size_t k) {
    if (is64) return (int)__builtin_nontemporal_load(&((const long long*)ei)[k]);
    return __builtin_nontemporal_load(&((const int*)ei)[k]);
}

// K1: per-node logits per head; zero pk nsum; init gmax.
__global__ void node_scores_kernel(const float* __restrict__ nf,
                                   const float* __restrict__ sfs,
                                   const float* __restrict__ sft,
                                   float* __restrict__ ss,
                                   float* __restrict__ st,
                                   unsigned* __restrict__ nsum_zero,
                                   unsigned* __restrict__ gmax,
                                   int NH, int nzero) {
    int i = blockIdx.x * blockDim.x + threadIdx.x;
    if (i >= NH) return;
    if (i == 0) *gmax = FENC_NEG_INF;
    for (int k = i; k < nzero; k += NH) nsum_zero[k] = 0u;
    int h = i & 3;
    const float4* __restrict__ row = (const float4*)(nf + (size_t)i * 32);
    const float4* __restrict__ as  = (const float4*)(sfs + h * 32);
    const float4* __restrict__ at  = (const float4*)(sft + h * 32);
    float accs = 0.f, acct = 0.f;
#pragma unroll
    for (int q = 0; q < 8; ++q) {
        float4 v = row[q];
        float4 a = as[q];
        float4 b = at[q];
        accs += v.x * a.x + v.y * a.y + v.z * a.z + v.w * a.w;
        acct += v.x * b.x + v.y * b.y + v.z * b.z + v.w * b.w;
    }
    ss[i] = accs;
    st[i] = acct;
}

// K2: per (edge, head-pair): p = exp(leaky_relu(ss+st)) for 2 heads, ONE pk
// bf16 atomic into nsum_pk; track running max. NO pbuf store (r12 change).
// Identity (validated r6+): exp(lr-c)/(S+eps) == exp(lr)/(S'+eps*e^c).
__global__ void edge_exp_sum_pk_kernel(const void* __restrict__ ei,
                                       const int* __restrict__ flag,
                                       const float* __restrict__ ss,
                                       const float* __restrict__ st,
                                       unsigned* __restrict__ nsum_pk,
                                       unsigned* __restrict__ gmax,
                                       int E) {
    __shared__ float red[256];
    int is64 = *flag;
    int n2 = E * 2;
    int stride = gridDim.x * blockDim.x;
    float lmax = -__builtin_inff();
    for (int i = blockIdx.x * blockDim.x + threadIdx.x; i < n2; i += stride) {
        int e = i >> 1, hp = i & 1;
        int trg = load_idx(ei, is64, e);
        int src = load_idx(ei, is64, (size_t)E + e);
        f32x2 a = *(const f32x2*)(ss + (size_t)src * 4 + hp * 2);
        f32x2 b = *(const f32x2*)(st + (size_t)trg * 4 + hp * 2);
        float s0 = a.x + b.x, s1 = a.y + b.y;
        float lr0 = s0 > 0.f ? s0 : NEG_SLOPE * s0;
        float lr1 = s1 > 0.f ? s1 : NEG_SLOPE * s1;
        lmax = fmaxf(lmax, fmaxf(lr0, lr1));
        float p0 = __expf(lr0), p1 = __expf(lr1);
        pk_atomic_add_bf16(nsum_pk + (size_t)trg * 2 + hp, p0, p1);
    }
    red[threadIdx.x] = lmax;
    __syncthreads();
    for (int off = 128; off > 0; off >>= 1) {
        if (threadIdx.x < off)
            red[threadIdx.x] = fmaxf(red[threadIdx.x], red[threadIdx.x + off]);
        __syncthreads();
    }
    if (threadIdx.x == 0) atomicMax(gmax, fenc(red[0]));
}

// K2b: per (node,head): rinv = 1 / (bf16_decode(nsum) + eps*e^c).
// Turns the per-edge divide into a multiply; 200k items, ~2us.
__global__ void rinv_kernel(const unsigned* __restrict__ nsum_pk,
                            const unsigned* __restrict__ gmax,
                            float* __restrict__ rinv,
                            int NH) {
    int i = blockIdx.x * blockDim.x + threadIdx.x;
    if (i >= NH) return;
    float de = EPSV * __expf(fdec(*gmax));
    unsigned u = nsum_pk[i >> 1];
    float d = (i & 1) ? __uint_as_float(u & 0xFFFF0000u)
                      : __uint_as_float((u & 0xFFFFu) << 16);
    rinv[i] = 1.f / (d + de);
}

// K3: att = exp(lr) * rinv[trg,h]; per (e,h), recompute keeps the numerator
// bit-identical to what K2 summed; nt store to out.
__global__ void att_rc_kernel(const void* __restrict__ ei,
                              const int* __restrict__ flag,
                              const float* __restrict__ ss,
                              const float* __restrict__ st,
                              const float* __restrict__ rinv,
                              float* __restrict__ out,
                              int E) {
    int is64 = *flag;
    int n4 = E * 4;
    int stride = gridDim.x * blockDim.x;
    for (int i = blockIdx.x * blockDim.x + threadIdx.x; i < n4; i += stride) {
        int e = i >> 2, h = i & 3;
        int trg = load_idx(ei, is64, e);
        int src = load_idx(ei, is64, (size_t)E + e);
        float s = ss[src * 4 + h] + st[trg * 4 + h];
        float lr = s > 0.f ? s : NEG_SLOPE * s;
        float a = __expf(lr) * rinv[trg * 4 + h];
        __builtin_nontemporal_store(a, &out[i]);
    }
}

// K4: feature gather; 32 lanes x 16B = 512B per edge, fully contiguous
// wave-level stores (r9-proven; 32B-strided variants regress), nt stores.
__global__ void gather_feat_kernel(const void* __restrict__ ei,
                                   const int* __restrict__ flag,
                                   const f32x4* __restrict__ nf4,
                                   f32x4* __restrict__ out4, int E) {
    int is64 = *flag;
    int n = E * 32;
    int stride = gridDim.x * blockDim.x;
    for (int t = blockIdx.x * blockDim.x + threadIdx.x; t < n; t += stride) {
        int e = t >> 5, q = t & 31;
        int src = load_idx(ei, is64, (size_t)E + e);
        f32x4 v = nf4[(size_t)src * 32 + q];
        __builtin_nontemporal_store(v, &out4[(size_t)e * 32 + q]);
    }
}

// ---------- fallback (ws too small): recompute pipeline, f32 atomics ----------
__device__ __forceinline__ float edge_lr_rc(const void* ei, int is64,
                                            const float* ss, const float* st,
                                            int E, int e, int h, int* trg_out) {
    int trg = load_idx(ei, is64, e);
    int src = load_idx(ei, is64, (size_t)E + e);
    if (trg_out) *trg_out = trg;
    float s = ss[src * 4 + h] + st[trg * 4 + h];
    return s > 0.f ? s : NEG_SLOPE * s;
}

__global__ void zero_fb_kernel(float* __restrict__ nsum, int n) {
    int i = blockIdx.x * blockDim.x + threadIdx.x;
    if (i < n) nsum[i] = 0.f;
}

__global__ void edge_exp_sum_fb_kernel(const void* __restrict__ ei,
                                       const int* __restrict__ flag,
                                       const float* __restrict__ ss,
                                       const float* __restrict__ st,
                                       float* __restrict__ nsum,
                                       unsigned* __restrict__ gmax, int E) {
    __shared__ float red[256];
    int is64 = *flag;
    int n4 = E * 4;
    int stride = gridDim.x * blockDim.x;
    float lmax = -__builtin_inff();
    for (int i = blockIdx.x * blockDim.x + threadIdx.x; i < n4; i += stride) {
        int trg;
        float lr = edge_lr_rc(ei, is64, ss, st, E, i >> 2, i & 3, &trg);
        lmax = fmaxf(lmax, lr);
        atomicAdd(&nsum[trg * 4 + (i & 3)], __expf(lr));
    }
    red[threadIdx.x] = lmax;
    __syncthreads();
    for (int off = 128; off > 0; off >>= 1) {
        if (threadIdx.x < off)
            red[threadIdx.x] = fmaxf(red[threadIdx.x], red[threadIdx.x + off]);
        __syncthreads();
    }
    if (threadIdx.x == 0) atomicMax(gmax, fenc(red[0]));
}

__global__ void att_fb_kernel(const void* __restrict__ ei,
                              const int* __restrict__ flag,
                              const float* __restrict__ ss,
                              const float* __restrict__ st,
                              const unsigned* __restrict__ gmax,
                              const float* __restrict__ nsum,
                              float* __restrict__ out, int E) {
    int i = blockIdx.x * blockDim.x + threadIdx.x;
    if (i >= E * 4) return;
    int is64 = *flag;
    float de = EPSV * __expf(fdec(*gmax));
    int trg;
    float lr = edge_lr_rc(ei, is64, ss, st, E, i >> 2, i & 3, &trg);
    float a = __expf(lr) / (nsum[trg * 4 + (i & 3)] + de);
    __builtin_nontemporal_store(a, &out[i]);
}

extern "C" void kernel_launch(void* const* d_in, const int* in_sizes, int n_in,
                              void* d_out, int out_size, void* d_ws, size_t ws_size,
                              hipStream_t stream) {
    const float* nf  = (const float*)d_in[0];
    const float* sfs = (const float*)d_in[1];
    const float* sft = (const float*)d_in[2];
    const void*  ei  = d_in[3];

    const int NH = in_sizes[0] / 32;   // N*H (F = 32)
    const int N  = NH / 4;
    const int E  = in_sizes[3] / 2;

    float* out = (float*)d_out;
    float* ws  = (float*)d_ws;

    // Layout: ss[NH] | st[NH] | flag,gmax,pad,pad | nsum_pk[N*2 u32] | rinv[NH]
    float*    ss      = ws;
    float*    st      = ws + NH;
    int*      flag    = (int*)(ws + 2 * (size_t)NH);
    unsigned* gmax    = (unsigned*)(flag + 1);
    unsigned* nsum_pk = (unsigned*)(ws + 2 * (size_t)NH + 4);
    float*    rinv    = (float*)(nsum_pk + (size_t)N * 2);

    size_t need = ((size_t)3 * NH + 4 + (size_t)N * 2) * 4;
    bool lean = ws_size >= need;

    const int B = 256;

    detect_idx_kernel<<<1, 256, 0, stream>>>((const unsigned*)ei, flag);

    if (lean) {
        node_scores_kernel<<<(NH + B - 1) / B, B, 0, stream>>>(
            nf, sfs, sft, ss, st, nsum_pk, gmax, NH, N * 2);
        edge_exp_sum_pk_kernel<<<2048, B, 0, stream>>>(ei, flag, ss, st,
                                                       nsum_pk, gmax, E);
        rinv_kernel<<<(NH + B - 1) / B, B, 0, stream>>>(nsum_pk, gmax, rinv, NH);
        att_rc_kernel<<<4096, B, 0, stream>>>(ei, flag, ss, st, rinv, out, E);
        gather_feat_kernel<<<4096, B, 0, stream>>>(
            ei, flag, (const f32x4*)nf, (f32x4*)(out + (size_t)E * 4), E);
    } else {
        // minimal-ws fallback: f32 nsum right after gmax
        float* nsum_fb = (float*)(gmax + 1);
        node_scores_kernel<<<(NH + B - 1) / B, B, 0, stream>>>(
            nf, sfs, sft, ss, st, (unsigned*)nsum_fb, gmax, NH, 0);
        zero_fb_kernel<<<(NH + B - 1) / B, B, 0, stream>>>(nsum_fb, NH);
        edge_exp_sum_fb_kernel<<<2048, B, 0, stream>>>(ei, flag, ss, st,
                                                       nsum_fb, gmax, E);
        att_fb_kernel<<<(E * 4 + B - 1) / B, B, 0, stream>>>(ei, flag, ss, st,
                                                             gmax, nsum_fb, out, E);
        gather_feat_kernel<<<4096, B, 0, stream>>>(
            ei, flag, (const f32x4*)nf, (f32x4*)(out + (size_t)E * 4), E);
    }
}